// Round 1
// baseline (479.153 us; speedup 1.0000x reference)
//
#include <hip/hip_runtime.h>

#define NSEQ   64
#define NHEAD  32
#define KVH    8
#define HS     128
#define BS     16
#define MBPS   64
#define MAXCTX 1024
#define QPKV   4
#define SCALE_F 0.08838834764831845f

__launch_bounds__(256)
__global__ void pa_kernel(const float* __restrict__ q,
                          const float* __restrict__ kc,
                          const float* __restrict__ vc,
                          const int*   __restrict__ bt,
                          const int*   __restrict__ cl,
                          float*       __restrict__ out)
{
    const int seq = blockIdx.x >> 3;   // 64 seqs
    const int kvh = blockIdx.x & 7;    // 8 kv heads
    const int t   = threadIdx.x;       // 0..255
    const int ctx = cl[seq];
    const int nb  = (ctx + BS - 1) / BS;

    // scores / probs for the 4 GQA heads; row padded +8 floats to dodge bank aliasing
    __shared__ __align__(16) float sc[QPKV][MAXCTX + 8];
    __shared__ float qs[QPKV][HS];
    __shared__ float l_inv[QPKV];

    // ---- stage the 4 query vectors for this kv head ----
    for (int i = t; i < QPKV * HS; i += 256) {
        int g = i >> 7, d = i & 127;
        qs[g][d] = q[((size_t)seq * NHEAD + kvh * QPKV + g) * HS + d];
    }
    __syncthreads();

    // ---- Pass 1: scores = (Q . K) * scale ----
    // key_cache elem (blk,kvh,d,tok) at (blk*KVH+kvh)*2048 + (d/8)*128 + tok*8 + d%8
    const int tok   = t >> 4;   // 0..15  token within page
    const int dpart = t & 15;   // 0..15  8-dim chunk (== d/8 thanks to X=8)
    float qreg[QPKV][8];
#pragma unroll
    for (int g = 0; g < QPKV; ++g)
#pragma unroll
        for (int j = 0; j < 8; ++j)
            qreg[g][j] = qs[g][dpart * 8 + j];

    const int* btrow = bt + seq * MBPS;
    for (int b = 0; b < nb; ++b) {
        const int blk = btrow[b];
        const float* kptr = kc + ((size_t)blk * KVH + kvh) * (HS * BS)
                               + dpart * (BS * 8) + tok * 8;
        const float4 k0 = *(const float4*)kptr;
        const float4 k1 = *(const float4*)(kptr + 4);
        const float kk[8] = {k0.x,k0.y,k0.z,k0.w,k1.x,k1.y,k1.z,k1.w};
        float p[QPKV];
#pragma unroll
        for (int g = 0; g < QPKV; ++g) {
            float s = 0.f;
#pragma unroll
            for (int j = 0; j < 8; ++j) s += qreg[g][j] * kk[j];
            p[g] = s;
        }
        // reduce the 16 dim-chunks (lanes dpart 0..15 within a 16-lane group)
#pragma unroll
        for (int off = 8; off >= 1; off >>= 1)
#pragma unroll
            for (int g = 0; g < QPKV; ++g)
                p[g] += __shfl_xor(p[g], off, 16);
        if (dpart < QPKV)
            sc[dpart][b * BS + tok] = p[dpart] * SCALE_F;
    }
    __syncthreads();

    // ---- softmax: one wave per query head ----
    {
        const int w    = t >> 6;  // head index 0..3
        const int lane = t & 63;
        float m = -1e30f;
        for (int i = lane; i < ctx; i += 64) m = fmaxf(m, sc[w][i]);
#pragma unroll
        for (int off = 32; off >= 1; off >>= 1) m = fmaxf(m, __shfl_xor(m, off));
        float ssum = 0.f;
        const int lim = nb * BS;
        for (int i = lane; i < lim; i += 64) {
            float v = (i < ctx) ? __expf(sc[w][i] - m) : 0.f;
            sc[w][i] = v;   // unnormalized prob; tail zeroed
            ssum += v;
        }
#pragma unroll
        for (int off = 32; off >= 1; off >>= 1) ssum += __shfl_xor(ssum, off);
        if (lane == 0) l_inv[w] = 1.f / ssum;
    }
    __syncthreads();

    // ---- Pass 2: O = P . V ----
    // value_cache elem (blk,kvh,d,tok) at (blk*KVH+kvh)*2048 + d*16 + tok
    const int d  = t >> 1;  // 0..127
    const int th = t & 1;   // token half (0: toks 0..7, 1: toks 8..15)
    float acc[QPKV] = {0.f, 0.f, 0.f, 0.f};
    for (int b = 0; b < nb; ++b) {
        const int blk = btrow[b];
        const float* vptr = vc + ((size_t)blk * KVH + kvh) * (HS * BS)
                               + d * BS + th * 8;
        const float4 v0 = *(const float4*)vptr;
        const float4 v1 = *(const float4*)(vptr + 4);
        const float vv[8] = {v0.x,v0.y,v0.z,v0.w,v1.x,v1.y,v1.z,v1.w};
        const int base = b * BS + th * 8;
#pragma unroll
        for (int g = 0; g < QPKV; ++g) {
            const float4 p0 = *(const float4*)&sc[g][base];
            const float4 p1 = *(const float4*)&sc[g][base + 4];
            acc[g] += p0.x*vv[0] + p0.y*vv[1] + p0.z*vv[2] + p0.w*vv[3]
                    + p1.x*vv[4] + p1.y*vv[5] + p1.z*vv[6] + p1.w*vv[7];
        }
    }
#pragma unroll
    for (int g = 0; g < QPKV; ++g)
        acc[g] += __shfl_xor(acc[g], 1);   // combine the two token halves
    if (th == 0) {
#pragma unroll
        for (int g = 0; g < QPKV; ++g)
            out[((size_t)seq * NHEAD + kvh * QPKV + g) * HS + d] = acc[g] * l_inv[g];
    }
}

extern "C" void kernel_launch(void* const* d_in, const int* in_sizes, int n_in,
                              void* d_out, int out_size, void* d_ws, size_t ws_size,
                              hipStream_t stream) {
    const float* query       = (const float*)d_in[0];
    const float* key_cache   = (const float*)d_in[1];
    const float* value_cache = (const float*)d_in[2];
    const int*   block_tables= (const int*)d_in[3];
    const int*   context_lens= (const int*)d_in[4];
    float* out = (float*)d_out;

    dim3 grid(NSEQ * KVH);
    dim3 block(256);
    pa_kernel<<<grid, block, 0, stream>>>(query, key_cache, value_cache,
                                          block_tables, context_lens, out);
}